// Round 15
// baseline (361.694 us; speedup 1.0000x reference)
//
#include <hip/hip_runtime.h>

#define DECAYF 0.99f
#define ONEMF 0.01f
#define EPSF 1e-5f

typedef __bf16 bf16x8 __attribute__((ext_vector_type(8)));
typedef float f32x4 __attribute__((ext_vector_type(4)));
typedef unsigned short ushort8 __attribute__((ext_vector_type(8)));

// ws layout (float indices):
// [0,65536)        dw accumulator (K*D)         -- zeroed by hipMemsetAsync
// [65536,66560)    counts (K)                   -- zeroed by hipMemsetAsync
// [67584]          sse                          -- zeroed by hipMemsetAsync
// [67585]          done-ticket (int)            -- zeroed by hipMemsetAsync
#define WS_COUNTS 65536
#define WS_SSE    67584
#define WS_DONE   67585

__device__ __forceinline__ float wave_reduce_add(float v) {
#pragma unroll
    for (int o = 32; o > 0; o >>= 1) v += __shfl_xor(v, o, 64);
    return v;
}

__device__ __forceinline__ unsigned short bf_rne(float f) {
    unsigned int u = __float_as_uint(f);
    unsigned int r = u + 0x7fffu + ((u >> 16) & 1u);
    return (unsigned short)(r >> 16);
}

// Split 8 f32 (two f32x4) into bf16 hi/lo ushort8s + sum of squares.
__device__ __forceinline__ void conv8(const f32x4 eA, const f32x4 eB,
                                      ushort8* hu, ushort8* lu, float* sq) {
    float s = 0.f;
    ushort8 h, l;
#pragma unroll
    for (int k = 0; k < 4; ++k) {
        const float f = eA[k];
        const unsigned short hh = bf_rne(f);
        h[k] = hh;
        l[k] = bf_rne(f - __uint_as_float((unsigned int)hh << 16));
        s += f * f;
    }
#pragma unroll
    for (int k = 0; k < 4; ++k) {
        const float f = eB[k];
        const unsigned short hh = bf_rne(f);
        h[4 + k] = hh;
        l[4 + k] = bf_rne(f - __uint_as_float((unsigned int)hh << 16));
        s += f * f;
    }
    *hu = h; *lu = l; *sq = s;
}

// Fused: MFMA scores + top-2 + fp64 re-rank + scatter outputs + (last block)
// the new_cs/loss epilogue. grid 512 x 256; each block = 128 tokens.
// R15 consolidation: prep_kernel deleted -- B is staged straight from f32 E
// with in-register bf16 hi/lo split + on-the-fly nchalf (4-lane shfl reduce);
// fin_cs folded into the last vq block via a device-scope ticket. The K-loop
// keeps the proven structure: LDS double-buffered 64-code chunks (XOR-swizzled
// rows), issue-early staging loads, lgkmcnt-only in-loop barriers.
__global__ __launch_bounds__(256, 2) void vq_main(const float* __restrict__ x,
                                                  const float* __restrict__ E,
                                                  const float* __restrict__ cs_in,
                                                  float* __restrict__ out,
                                                  float* __restrict__ ws) {
    const int tid = threadIdx.x;
    const int lane = tid & 63;
    const int w = tid >> 6;
    const int q = lane >> 4, m = lane & 15;
    const int blk = blockIdx.x;
    const int b = blk >> 5;            // batch
    const int hw0 = (blk & 31) << 7;   // hw offset (128 tokens)
    const int tok0 = blk << 7;

    __shared__ float xs[128 * 68];     // [token][dim], stride 68: rows 16B-aligned
    __shared__ int i1sh[128], i2sh[128], idx_sh[128];
    // Double-buffered 64-code chunk: [hi 8192B][lo 8192B][nchalf 256B].
    // After the K-loop reused as eqb[128][65] (33280B needed).
    __shared__ char lds_b[2][16640];
    __shared__ float redn[4];
    __shared__ int last_sh;

    float* enc = out + 1 + (size_t)4194304;

    // Stage x tile (fully coalesced: consecutive tid -> consecutive hw).
    {
        const float* xb = x + ((size_t)b << 18) + hw0;
#pragma unroll
        for (int cc = 0; cc < 32; ++cc) {
            const int id = cc * 256 + tid;
            const int c = id >> 7, t = id & 127;
            xs[t * 68 + c] = xb[((size_t)c << 12) + t];
        }
    }

    // B-staging geometry: thread owns 8-dim groups v0=2*tid, v1=2*tid+1 of the
    // 512 groups per 64-code chunk. code cl0 = tid>>2 (same for both groups);
    // XOR-swizzle: phys group = g ^ (cl&7).
    const int cl0 = tid >> 2;
    const int gA = (tid * 2) & 7, gB = gA + 1;
    const int dstA = cl0 * 128 + ((gA ^ (cl0 & 7)) << 4);
    const int dstB = cl0 * 128 + ((gB ^ (cl0 & 7)) << 4);

    // Prologue: stage chunk 0 (codes 0..63) straight from f32 E.
    {
        const float* Eb0 = E + tid * 16;
        const f32x4 eA0 = *(const f32x4*)(Eb0);
        const f32x4 eB0 = *(const f32x4*)(Eb0 + 4);
        const f32x4 eA1 = *(const f32x4*)(Eb0 + 8);
        const f32x4 eB1 = *(const f32x4*)(Eb0 + 12);
        ushort8 h0, l0, h1, l1; float s0, s1;
        conv8(eA0, eB0, &h0, &l0, &s0);
        conv8(eA1, eB1, &h1, &l1, &s1);
        *(ushort8*)(lds_b[0] + dstA)        = h0;
        *(ushort8*)(lds_b[0] + dstB)        = h1;
        *(ushort8*)(lds_b[0] + 8192 + dstA) = l0;
        *(ushort8*)(lds_b[0] + 8192 + dstB) = l1;
        float sc = s0 + s1;
        sc += __shfl_xor(sc, 1, 64);
        sc += __shfl_xor(sc, 2, 64);
        if ((tid & 3) == 0) *(float*)(lds_b[0] + 16384 + cl0 * 4) = -0.5f * sc;
    }
    __syncthreads();

    // A fragments: 2 row-tiles (16 tokens each) x 2 K-slices x (hi,lo).
    bf16x8 Ah[2][2], Al[2][2];
#pragma unroll
    for (int t = 0; t < 2; ++t) {
        const int tok = w * 32 + t * 16 + m;
#pragma unroll
        for (int s = 0; s < 2; ++s) {
            const float* p = &xs[tok * 68 + s * 32 + q * 8];
            ushort8 hu, lu;
#pragma unroll
            for (int j = 0; j < 8; ++j) {
                const float f = p[j];
                const unsigned short h = bf_rne(f);
                const float hf = __uint_as_float((unsigned int)h << 16);
                hu[j] = h;
                lu[j] = bf_rne(f - hf);
            }
            Ah[t][s] = __builtin_bit_cast(bf16x8, hu);
            Al[t][s] = __builtin_bit_cast(bf16x8, lu);
        }
    }

    // Per-lane running top-2 per C/D row (4 regs x 2 tiles).
    float b1[2][4], b2[2][4];
    int i1[2][4], i2[2][4];
#pragma unroll
    for (int t = 0; t < 2; ++t)
#pragma unroll
        for (int r = 0; r < 4; ++r) { b1[t][r] = -1e30f; b2[t][r] = -1e30f; i1[t][r] = 0; i2[t][r] = 1; }

    const f32x4 z4 = {0.0f, 0.0f, 0.0f, 0.0f};
    const int hm = m & 7;
    const int off0 = (q ^ hm) << 4;           // group q   (dims q*8..)
    const int off1 = ((4 + q) ^ hm) << 4;     // group 4+q (dims 32+q*8..)

    // 16 chunks x 4 steps. Issue-early next-chunk f32 loads at chunk open;
    // convert + ds_write late; barrier WITHOUT vmcnt drain.
    for (int kc = 0; kc < 16; ++kc) {
        f32x4 eA0 = z4, eB0 = z4, eA1 = z4, eB1 = z4;
        if (kc < 15) {
            const float* Ebn = E + (kc + 1) * 4096 + tid * 16;
            eA0 = *(const f32x4*)(Ebn);
            eB0 = *(const f32x4*)(Ebn + 4);
            eA1 = *(const f32x4*)(Ebn + 8);
            eB1 = *(const f32x4*)(Ebn + 12);
        }
        const char* bufc = lds_b[kc & 1];

#define VQ_STEP(S)                                                              \
    {                                                                           \
        const int cl = (S) * 16 + m;                                            \
        const char* rowp = bufc + cl * 128;                                     \
        const bf16x8 bh0 = *(const bf16x8*)(rowp + off0);                       \
        const bf16x8 bh1 = *(const bf16x8*)(rowp + off1);                       \
        const bf16x8 bl0 = *(const bf16x8*)(rowp + 8192 + off0);                \
        const bf16x8 bl1 = *(const bf16x8*)(rowp + 8192 + off1);                \
        const float nc = *(const float*)(bufc + 16384 + cl * 4);                \
        const int idx = kc * 64 + cl;                                           \
        _Pragma("unroll")                                                       \
        for (int t = 0; t < 2; ++t) {                                           \
            f32x4 acc = {nc, nc, nc, nc}; /* score = x.e - 0.5||e||^2 */        \
            acc = __builtin_amdgcn_mfma_f32_16x16x32_bf16(Ah[t][0], bh0, acc, 0, 0, 0); \
            acc = __builtin_amdgcn_mfma_f32_16x16x32_bf16(Ah[t][1], bh1, acc, 0, 0, 0); \
            acc = __builtin_amdgcn_mfma_f32_16x16x32_bf16(Al[t][0], bh0, acc, 0, 0, 0); \
            acc = __builtin_amdgcn_mfma_f32_16x16x32_bf16(Al[t][1], bh1, acc, 0, 0, 0); \
            acc = __builtin_amdgcn_mfma_f32_16x16x32_bf16(Ah[t][0], bl0, acc, 0, 0, 0); \
            acc = __builtin_amdgcn_mfma_f32_16x16x32_bf16(Ah[t][1], bl1, acc, 0, 0, 0); \
            _Pragma("unroll")                                                   \
            for (int r = 0; r < 4; ++r) {                                       \
                const float s = acc[r];                                         \
                const bool cA = s > b1[t][r];                                   \
                const bool cB = s > b2[t][r];                                   \
                b2[t][r] = cA ? b1[t][r] : (cB ? s : b2[t][r]);                 \
                i2[t][r] = cA ? i1[t][r] : (cB ? idx : i2[t][r]);               \
                b1[t][r] = cA ? s : b1[t][r];                                   \
                i1[t][r] = cA ? idx : i1[t][r];                                 \
            }                                                                   \
        }                                                                       \
    }

        VQ_STEP(0)
        VQ_STEP(1)
        VQ_STEP(2)
        VQ_STEP(3)
#undef VQ_STEP

        if (kc < 15) {
            char* bufn = lds_b[(kc + 1) & 1];
            ushort8 h0, l0, h1, l1; float s0, s1;
            conv8(eA0, eB0, &h0, &l0, &s0);
            conv8(eA1, eB1, &h1, &l1, &s1);
            *(ushort8*)(bufn + dstA)        = h0;   // counted vmcnt (reg dep on
            *(ushort8*)(bufn + dstB)        = h1;   // the early loads)
            *(ushort8*)(bufn + 8192 + dstA) = l0;
            *(ushort8*)(bufn + 8192 + dstB) = l1;
            float sc = s0 + s1;
            sc += __shfl_xor(sc, 1, 64);
            sc += __shfl_xor(sc, 2, 64);
            if ((tid & 3) == 0) *(float*)(bufn + 16384 + cl0 * 4) = -0.5f * sc;
        }
        // Barrier WITHOUT vmcnt(0): order LDS ops only.
        asm volatile("s_waitcnt lgkmcnt(0)" ::: "memory");
        __builtin_amdgcn_s_barrier();
        __builtin_amdgcn_sched_barrier(0);
    }

    // Merge top-2 across the 16 lanes of each quad-group (cols of the row).
#pragma unroll
    for (int d = 1; d < 16; d <<= 1) {
#pragma unroll
        for (int t = 0; t < 2; ++t)
#pragma unroll
            for (int r = 0; r < 4; ++r) {
                const float ob1 = __shfl_xor(b1[t][r], d, 64);
                const int   oi1 = __shfl_xor(i1[t][r], d, 64);
                const float ob2 = __shfl_xor(b2[t][r], d, 64);
                const int   oi2 = __shfl_xor(i2[t][r], d, 64);
                const bool wv = ob1 > b1[t][r];
                const float t1 = wv ? ob1 : b1[t][r]; const int ti1 = wv ? oi1 : i1[t][r];
                const float sA = wv ? b1[t][r] : ob1; const int siA = wv ? i1[t][r] : oi1;
                const float sB = wv ? ob2 : b2[t][r]; const int siB = wv ? oi2 : i2[t][r];
                const bool w2 = sB > sA;
                b1[t][r] = t1; i1[t][r] = ti1;
                b2[t][r] = w2 ? sB : sA; i2[t][r] = w2 ? siB : siA;
            }
    }
    if (m == 0) {   // quad leaders publish rows 4q+r of each tile
#pragma unroll
        for (int t = 0; t < 2; ++t)
#pragma unroll
            for (int r = 0; r < 4; ++r) {
                const int tokL = w * 32 + t * 16 + q * 4 + r;
                i1sh[tokL] = i1[t][r];
                i2sh[tokL] = i2[t][r];
            }
    }

    // fp64 re-rank of the two candidates (same wave -> no barrier needed).
    float dval = 0.0f;
    if (lane < 32) {
        const int tokL = w * 32 + lane;
        const int I1 = i1sh[tokL], I2 = i2sh[tokL];
        const int ca = I1 < I2 ? I1 : I2;
        const int cb = I1 < I2 ? I2 : I1;
        const float* Ea = E + ca * 64;
        const float* Eb = E + cb * 64;
        const float* xr = &xs[tokL * 68];
        double sa = 0, ea = 0, sb = 0, eb = 0, x2 = 0;
#pragma unroll 8
        for (int c = 0; c < 64; ++c) {
            const double xv = (double)xr[c];
            const double va = (double)Ea[c], vb = (double)Eb[c];
            sa += xv * va; ea += va * va;
            sb += xv * vb; eb += vb * vb;
            x2 += xv * xv;
        }
        const double qa = ea - 2.0 * sa;
        const double qb = eb - 2.0 * sb;
        int best; double qq;
        if (qb < qa) { best = cb; qq = qb; } else { best = ca; qq = qa; }
        idx_sh[tokL] = best;
        float dd = (float)(qq + x2);
        dval = dd < 0.f ? 0.f : dd;
        atomicAdd(&ws[WS_COUNTS + best], 1.0f);
    }
    const float ssum = wave_reduce_add(dval);
    if (lane == 0) atomicAdd(&ws[WS_SSE], ssum);
    __syncthreads();   // idx_sh visibility + drains all outstanding vm ops

    // Sparse one-hot 1.0 entries (enc region is zero from the harness reset).
    if (tid < 128) {
        const int kb = idx_sh[tid];
        enc[(size_t)(tok0 + tid) * 1024 + kb] = 1.0f;
    }

    // Stage quantized rows coalesced: wave w copies rows idx_sh[w*32..+31],
    // 64-lane row reads into eqb (aliasing the dead lds_b buffer).
    float* eqb = (float*)lds_b;       // [128][65], 33280B <= sizeof(lds_b)
#pragma unroll
    for (int j = 0; j < 32; ++j) {
        const int t = w * 32 + j;
        eqb[t * 65 + lane] = E[idx_sh[t] * 64 + lane];
    }
    asm volatile("s_waitcnt lgkmcnt(0)" ::: "memory");
    __builtin_amdgcn_s_barrier();     // LDS-only barrier (no vmcnt drain)

    // q_st output (reference order: x + (e - x)); plain coalesced stores.
    float* outq = out + 1;
#pragma unroll
    for (int cc = 0; cc < 32; ++cc) {
        const int id = cc * 256 + tid;
        const int c = id >> 7, t = id & 127;
        const float xv = xs[t * 68 + c];
        const float eq = eqb[t * 65 + c];
        outq[((size_t)(b * 64 + c) << 12) + hw0 + t] = xv + (eq - xv);
    }
    // dw scatter-add: lane = dim (coalesced atomics), wave-uniform row.
#pragma unroll 4
    for (int tt = 0; tt < 32; ++tt) {
        const int t = w * 32 + tt;
        const int kb = idx_sh[t];
        atomicAdd(&ws[kb * 64 + lane], xs[t * 68 + lane]);
    }

    // ---- Last-block epilogue (replaces fin_cs kernel) ----
    __syncthreads();                  // all this block's atomics retired
    if (tid == 0) {
        __threadfence();              // release: publish our atomics
        const int old = atomicAdd((int*)ws + WS_DONE, 1);
        last_sh = (old == 511);
    }
    __syncthreads();
    if (last_sh) {
        __threadfence();              // acquire: see all blocks' counts/sse
        float raw[4];
        float nloc = 0.f;
#pragma unroll
        for (int k2 = 0; k2 < 4; ++k2) {
            const int i = k2 * 256 + tid;
            const float r = cs_in[i] * DECAYF + ONEMF * ws[WS_COUNTS + i];
            raw[k2] = r;
            nloc += r;
        }
        const float swv = wave_reduce_add(nloc);
        if (lane == 0) redn[w] = swv;
        __syncthreads();
        const float n = redn[0] + redn[1] + redn[2] + redn[3];
        if (tid == 0) out[0] = 0.25f * ws[WS_SSE] * (1.0f / 4194304.0f);  // loss
#pragma unroll
        for (int k2 = 0; k2 < 4; ++k2) {
            const int i = k2 * 256 + tid;
            out[71368705 + i] = (raw[k2] + EPSF) / (n + 1024.0f * EPSF) * n;
        }
    }
}

// new_ema_weight and new_embedding. grid 256 x 256.
__global__ __launch_bounds__(256) void fin_w(const float* __restrict__ emaw,
                                             float* __restrict__ out,
                                             const float* __restrict__ ws) {
    const int i = blockIdx.x * 256 + threadIdx.x;
    const float val = emaw[i] * DECAYF + ONEMF * ws[i];
    out[71369729 + i] = val;                               // new_ema_weight
    const float cs = out[71368705 + (i >> 6)];             // new_cs (from vq_main last block)
    out[71303169 + i] = val / cs;                          // new_embedding
}

extern "C" void kernel_launch(void* const* d_in, const int* in_sizes, int n_in,
                              void* d_out, int out_size, void* d_ws, size_t ws_size,
                              hipStream_t stream) {
    const float* x    = (const float*)d_in[0];   // [16,64,64,64]
    const float* E    = (const float*)d_in[1];   // [1024,64]
    const float* cs   = (const float*)d_in[2];   // [1024]
    const float* emaw = (const float*)d_in[3];   // [1024,64]
    float* out = (float*)d_out;
    float* ws  = (float*)d_ws;

    hipMemsetAsync(ws, 0, (size_t)(WS_DONE + 1) * 4, stream);  // dw+counts+sse+ticket
    vq_main<<<512, 256, 0, stream>>>(x, E, cs, out, ws);
    fin_w<<<256, 256, 0, stream>>>(emaw, out, ws);
}

// Round 16
// 353.919 us; speedup vs baseline: 1.0220x; 1.0220x over previous
//
#include <hip/hip_runtime.h>

#define DECAYF 0.99f
#define ONEMF 0.01f
#define EPSF 1e-5f

typedef __bf16 bf16x8 __attribute__((ext_vector_type(8)));
typedef float f32x4 __attribute__((ext_vector_type(4)));
typedef unsigned short ushort8 __attribute__((ext_vector_type(8)));

// ws layout (float indices):
// [0,65536)        dw accumulator (K*D)
// [65536,66560)    counts (K)
// [66560,67584)    nchalf = -0.5*||e_k||^2
// [67584]          sse
// [67600,100368)   E_hi as bf16 (ushort), PRE-SWIZZLED chunk-major layout
// [100368,133136)  E_lo as bf16 (ushort), same layout
#define WS_COUNTS 65536
#define WS_NCHALF 66560
#define WS_SSE    67584
#define WS_EHI    67600
#define WS_ELO    100368

__device__ __forceinline__ float wave_reduce_add(float v) {
#pragma unroll
    for (int o = 32; o > 0; o >>= 1) v += __shfl_xor(v, o, 64);
    return v;
}

__device__ __forceinline__ unsigned short bf_rne(float f) {
    unsigned int u = __float_as_uint(f);
    unsigned int r = u + 0x7fffu + ((u >> 16) & 1u);
    return (unsigned short)(r >> 16);
}

// Async global->LDS DMA: dest = lds_base (wave-uniform) + lane*size.
__device__ __forceinline__ void gload16(const void* g, void* l) {
    __builtin_amdgcn_global_load_lds(
        (const __attribute__((address_space(1))) void*)g,
        (__attribute__((address_space(3))) void*)l, 16, 0, 0);
}
__device__ __forceinline__ void gload4(const void* g, void* l) {
    __builtin_amdgcn_global_load_lds(
        (const __attribute__((address_space(1))) void*)g,
        (__attribute__((address_space(3))) void*)l, 4, 0, 0);
}

// Prep: split E into bf16 hi/lo written in the PRE-SWIZZLED linear order the
// K-loop's global_load_lds expects (unit u: code cl=u>>3, logical group
// g=(u&7)^(cl&7)); nchalf via 8-lane shfl reduce; zero dw/counts/sse.
// grid 32 x 256 (8192 threads = 1024 codes x 8 groups).
__global__ __launch_bounds__(256) void prep_kernel(const float* __restrict__ E,
                                                   float* __restrict__ ws) {
    const int U = blockIdx.x * 256 + threadIdx.x;   // global 16B unit
    const int code = U >> 3;
    const int g = (U & 7) ^ (code & 7);             // logical group at this slot
    const float* src = E + code * 64 + g * 8;
    const f32x4 eA = *(const f32x4*)(src);
    const f32x4 eB = *(const f32x4*)(src + 4);
    ushort8 h, l;
    float s = 0.f;
#pragma unroll
    for (int k = 0; k < 4; ++k) {
        const float f = eA[k];
        const unsigned short hh = bf_rne(f);
        h[k] = hh;
        l[k] = bf_rne(f - __uint_as_float((unsigned int)hh << 16));
    }
#pragma unroll
    for (int k = 0; k < 4; ++k) {
        const float f = eB[k];
        const unsigned short hh = bf_rne(f);
        h[4 + k] = hh;
        l[4 + k] = bf_rne(f - __uint_as_float((unsigned int)hh << 16));
    }
    ((ushort8*)(ws + WS_EHI))[U] = h;
    ((ushort8*)(ws + WS_ELO))[U] = l;
    // nchalf: full squared norm of this code's logical groups; the 8 threads
    // of one code are consecutive lanes -> 8-lane shfl reduce. Sum uses the
    // ORIGINAL f32 values (same as before).
#pragma unroll
    for (int k = 0; k < 4; ++k) s += eA[k] * eA[k] + eB[k] * eB[k];
    s += __shfl_xor(s, 1, 64);
    s += __shfl_xor(s, 2, 64);
    s += __shfl_xor(s, 4, 64);
    if ((U & 7) == 0) ws[WS_NCHALF + code] = -0.5f * s;
    // zeroing: dw (8 floats/thread), counts, sse.
    ((f32x4*)ws)[U * 2] = (f32x4){0.f, 0.f, 0.f, 0.f};
    ((f32x4*)ws)[U * 2 + 1] = (f32x4){0.f, 0.f, 0.f, 0.f};
    if (U < 1024) ws[WS_COUNTS + U] = 0.0f;
    if (U == 0) ws[WS_SSE] = 0.0f;
}

// Main: MFMA scores + top-2 + fp64 re-rank + scatter outputs.
// grid 512 x 256; each block = 128 tokens (best-measured geometry).
// R16 change: chunk staging via global_load_lds (async DMA, no VGPR round
// trip, no ds_write in the lgkm domain) from the pre-swizzled ws layout.
// The loop has NO other vm ops, so the pre-barrier vmcnt(0) waits only on
// DMAs issued a full chunk earlier -> zero stall (clean T4).
__global__ __launch_bounds__(256, 2) void vq_main(const float* __restrict__ x,
                                                  const float* __restrict__ E,
                                                  float* __restrict__ out,
                                                  float* __restrict__ ws) {
    const int tid = threadIdx.x;
    const int lane = tid & 63;
    const int w = tid >> 6;
    const int q = lane >> 4, m = lane & 15;
    const int blk = blockIdx.x;
    const int b = blk >> 5;            // batch
    const int hw0 = (blk & 31) << 7;   // hw offset (128 tokens)
    const int tok0 = blk << 7;

    __shared__ float xs[128 * 68];     // [token][dim], stride 68: rows 16B-aligned
    __shared__ int i1sh[128], i2sh[128], idx_sh[128];
    // Double-buffered 64-code chunk: [hi 8192B][lo 8192B][nchalf 256B].
    // After the K-loop reused as eqb[128][65] (33280B needed).
    __shared__ char lds_b[2][16640];

    float* enc = out + 1 + (size_t)4194304;

    const char* ehis = (const char*)(ws + WS_EHI);
    const char* elos = (const char*)(ws + WS_ELO);
    const float* __restrict__ ncp = ws + WS_NCHALF;

    // Stage x tile (fully coalesced: consecutive tid -> consecutive hw).
    {
        const float* xb = x + ((size_t)b << 18) + hw0;
#pragma unroll
        for (int cc = 0; cc < 32; ++cc) {
            const int id = cc * 256 + tid;
            const int c = id >> 7, t = id & 127;
            xs[t * 68 + c] = xb[((size_t)c << 12) + t];
        }
    }

    // Prologue: issue chunk-0 DMA (wave w covers 2 KB of hi and of lo).
    {
        const int wo = w * 2048 + lane * 16;
        gload16(ehis + wo,        lds_b[0] + w * 2048);
        gload16(ehis + wo + 1024, lds_b[0] + w * 2048 + 1024);
        gload16(elos + wo,        lds_b[0] + 8192 + w * 2048);
        gload16(elos + wo + 1024, lds_b[0] + 8192 + w * 2048 + 1024);
        if (w == 0) gload4(ncp + lane, lds_b[0] + 16384);
    }
    __syncthreads();   // full drain: xs ds_writes + chunk-0 DMA

    // A fragments: 2 row-tiles (16 tokens each) x 2 K-slices x (hi,lo).
    bf16x8 Ah[2][2], Al[2][2];
#pragma unroll
    for (int t = 0; t < 2; ++t) {
        const int tok = w * 32 + t * 16 + m;
#pragma unroll
        for (int s = 0; s < 2; ++s) {
            const float* p = &xs[tok * 68 + s * 32 + q * 8];
            ushort8 hu, lu;
#pragma unroll
            for (int j = 0; j < 8; ++j) {
                const float f = p[j];
                const unsigned short h = bf_rne(f);
                const float hf = __uint_as_float((unsigned int)h << 16);
                hu[j] = h;
                lu[j] = bf_rne(f - hf);
            }
            Ah[t][s] = __builtin_bit_cast(bf16x8, hu);
            Al[t][s] = __builtin_bit_cast(bf16x8, lu);
        }
    }

    // Per-lane running top-2 per C/D row (4 regs x 2 tiles).
    float b1[2][4], b2[2][4];
    int i1[2][4], i2[2][4];
#pragma unroll
    for (int t = 0; t < 2; ++t)
#pragma unroll
        for (int r = 0; r < 4; ++r) { b1[t][r] = -1e30f; b2[t][r] = -1e30f; i1[t][r] = 0; i2[t][r] = 1; }

    const int hm = m & 7;
    const int off0 = (q ^ hm) << 4;           // group q   (dims q*8..)
    const int off1 = ((4 + q) ^ hm) << 4;     // group 4+q (dims 32+q*8..)

    // 16 chunks x 4 steps. DMA for chunk kc+1 issued at chunk top; barrier
    // waits vmcnt(0) (only our DMAs) + lgkmcnt(0).
    for (int kc = 0; kc < 16; ++kc) {
        if (kc < 15) {
            const int cb = (kc + 1) * 8192;
            const int wo = w * 2048 + lane * 16;
            char* bufn = lds_b[(kc + 1) & 1];
            gload16(ehis + cb + wo,        bufn + w * 2048);
            gload16(ehis + cb + wo + 1024, bufn + w * 2048 + 1024);
            gload16(elos + cb + wo,        bufn + 8192 + w * 2048);
            gload16(elos + cb + wo + 1024, bufn + 8192 + w * 2048 + 1024);
            if (w == 0) gload4(ncp + (kc + 1) * 64 + lane, bufn + 16384);
        }
        const char* bufc = lds_b[kc & 1];

#define VQ_STEP(S)                                                              \
    {                                                                           \
        const int cl = (S) * 16 + m;                                            \
        const char* rowp = bufc + cl * 128;                                     \
        const bf16x8 bh0 = *(const bf16x8*)(rowp + off0);                       \
        const bf16x8 bh1 = *(const bf16x8*)(rowp + off1);                       \
        const bf16x8 bl0 = *(const bf16x8*)(rowp + 8192 + off0);                \
        const bf16x8 bl1 = *(const bf16x8*)(rowp + 8192 + off1);                \
        const float nc = *(const float*)(bufc + 16384 + cl * 4);                \
        const int idx = kc * 64 + cl;                                           \
        _Pragma("unroll")                                                       \
        for (int t = 0; t < 2; ++t) {                                           \
            f32x4 acc = {nc, nc, nc, nc}; /* score = x.e - 0.5||e||^2 */        \
            acc = __builtin_amdgcn_mfma_f32_16x16x32_bf16(Ah[t][0], bh0, acc, 0, 0, 0); \
            acc = __builtin_amdgcn_mfma_f32_16x16x32_bf16(Ah[t][1], bh1, acc, 0, 0, 0); \
            acc = __builtin_amdgcn_mfma_f32_16x16x32_bf16(Al[t][0], bh0, acc, 0, 0, 0); \
            acc = __builtin_amdgcn_mfma_f32_16x16x32_bf16(Al[t][1], bh1, acc, 0, 0, 0); \
            acc = __builtin_amdgcn_mfma_f32_16x16x32_bf16(Ah[t][0], bl0, acc, 0, 0, 0); \
            acc = __builtin_amdgcn_mfma_f32_16x16x32_bf16(Ah[t][1], bl1, acc, 0, 0, 0); \
            _Pragma("unroll")                                                   \
            for (int r = 0; r < 4; ++r) {                                       \
                const float s = acc[r];                                         \
                const bool cA = s > b1[t][r];                                   \
                const bool cB = s > b2[t][r];                                   \
                b2[t][r] = cA ? b1[t][r] : (cB ? s : b2[t][r]);                 \
                i2[t][r] = cA ? i1[t][r] : (cB ? idx : i2[t][r]);               \
                b1[t][r] = cA ? s : b1[t][r];                                   \
                i1[t][r] = cA ? idx : i1[t][r];                                 \
            }                                                                   \
        }                                                                       \
    }

        VQ_STEP(0)
        VQ_STEP(1)
        VQ_STEP(2)
        VQ_STEP(3)
#undef VQ_STEP

        // Barrier: wait our prefetch DMAs (issued a chunk ago) + LDS ops.
        asm volatile("s_waitcnt vmcnt(0) lgkmcnt(0)" ::: "memory");
        __builtin_amdgcn_s_barrier();
        __builtin_amdgcn_sched_barrier(0);
    }

    // Merge top-2 across the 16 lanes of each quad-group (cols of the row).
#pragma unroll
    for (int d = 1; d < 16; d <<= 1) {
#pragma unroll
        for (int t = 0; t < 2; ++t)
#pragma unroll
            for (int r = 0; r < 4; ++r) {
                const float ob1 = __shfl_xor(b1[t][r], d, 64);
                const int   oi1 = __shfl_xor(i1[t][r], d, 64);
                const float ob2 = __shfl_xor(b2[t][r], d, 64);
                const int   oi2 = __shfl_xor(i2[t][r], d, 64);
                const bool wv = ob1 > b1[t][r];
                const float t1 = wv ? ob1 : b1[t][r]; const int ti1 = wv ? oi1 : i1[t][r];
                const float sA = wv ? b1[t][r] : ob1; const int siA = wv ? i1[t][r] : oi1;
                const float sB = wv ? ob2 : b2[t][r]; const int siB = wv ? oi2 : i2[t][r];
                const bool w2 = sB > sA;
                b1[t][r] = t1; i1[t][r] = ti1;
                b2[t][r] = w2 ? sB : sA; i2[t][r] = w2 ? siB : siA;
            }
    }
    if (m == 0) {   // quad leaders publish rows 4q+r of each tile
#pragma unroll
        for (int t = 0; t < 2; ++t)
#pragma unroll
            for (int r = 0; r < 4; ++r) {
                const int tokL = w * 32 + t * 16 + q * 4 + r;
                i1sh[tokL] = i1[t][r];
                i2sh[tokL] = i2[t][r];
            }
    }

    // fp64 re-rank of the two candidates (same wave -> no barrier needed).
    float dval = 0.0f;
    if (lane < 32) {
        const int tokL = w * 32 + lane;
        const int I1 = i1sh[tokL], I2 = i2sh[tokL];
        const int ca = I1 < I2 ? I1 : I2;
        const int cb = I1 < I2 ? I2 : I1;
        const float* Ea = E + ca * 64;
        const float* Eb = E + cb * 64;
        const float* xr = &xs[tokL * 68];
        double sa = 0, ea = 0, sb = 0, eb = 0, x2 = 0;
#pragma unroll 8
        for (int c = 0; c < 64; ++c) {
            const double xv = (double)xr[c];
            const double va = (double)Ea[c], vb = (double)Eb[c];
            sa += xv * va; ea += va * va;
            sb += xv * vb; eb += vb * vb;
            x2 += xv * xv;
        }
        const double qa = ea - 2.0 * sa;
        const double qb = eb - 2.0 * sb;
        int best; double qq;
        if (qb < qa) { best = cb; qq = qb; } else { best = ca; qq = qa; }
        idx_sh[tokL] = best;
        float dd = (float)(qq + x2);
        dval = dd < 0.f ? 0.f : dd;
        atomicAdd(&ws[WS_COUNTS + best], 1.0f);
    }
    const float ssum = wave_reduce_add(dval);
    if (lane == 0) atomicAdd(&ws[WS_SSE], ssum);
    __syncthreads();   // idx_sh visibility + drains outstanding vm ops

    // Sparse one-hot 1.0 entries (enc region is zero from the harness reset).
    if (tid < 128) {
        const int kb = idx_sh[tid];
        enc[(size_t)(tok0 + tid) * 1024 + kb] = 1.0f;
    }

    // Stage quantized rows coalesced: wave w copies rows idx_sh[w*32..+31],
    // 64-lane row reads into eqb (aliasing the dead lds_b buffer).
    float* eqb = (float*)lds_b;       // [128][65], 33280B <= sizeof(lds_b)
#pragma unroll
    for (int j = 0; j < 32; ++j) {
        const int t = w * 32 + j;
        eqb[t * 65 + lane] = E[idx_sh[t] * 64 + lane];
    }
    asm volatile("s_waitcnt lgkmcnt(0)" ::: "memory");
    __builtin_amdgcn_s_barrier();     // LDS-only barrier (no vmcnt drain)

    // q_st output (reference order: x + (e - x)); plain coalesced stores.
    float* outq = out + 1;
#pragma unroll
    for (int cc = 0; cc < 32; ++cc) {
        const int id = cc * 256 + tid;
        const int c = id >> 7, t = id & 127;
        const float xv = xs[t * 68 + c];
        const float eq = eqb[t * 65 + c];
        outq[((size_t)(b * 64 + c) << 12) + hw0 + t] = xv + (eq - xv);
    }
    // dw scatter-add: lane = dim (coalesced atomics), wave-uniform row.
#pragma unroll 4
    for (int tt = 0; tt < 32; ++tt) {
        const int t = w * 32 + tt;
        const int kb = idx_sh[t];
        atomicAdd(&ws[kb * 64 + lane], xs[t * 68 + lane]);
    }
}

// new_cs (Laplace-smoothed) + loss. 1 block x 1024.
__global__ __launch_bounds__(1024) void fin_cs(const float* __restrict__ cs_in,
                                               float* __restrict__ out,
                                               const float* __restrict__ ws) {
    __shared__ float red[16];
    __shared__ float n_sh;
    const int tid = threadIdx.x;
    const float raw = cs_in[tid] * DECAYF + ONEMF * ws[WS_COUNTS + tid];
    const float s = wave_reduce_add(raw);
    if ((tid & 63) == 0) red[tid >> 6] = s;
    __syncthreads();
    if (tid == 0) {
        float n = 0.f;
#pragma unroll
        for (int i = 0; i < 16; ++i) n += red[i];
        n_sh = n;
        out[0] = 0.25f * ws[WS_SSE] * (1.0f / 4194304.0f);  // loss
    }
    __syncthreads();
    const float n = n_sh;
    out[71368705 + tid] = (raw + EPSF) / (n + 1024.0f * EPSF) * n;
}

// new_ema_weight and new_embedding. grid 256 x 256.
__global__ __launch_bounds__(256) void fin_w(const float* __restrict__ emaw,
                                             float* __restrict__ out,
                                             const float* __restrict__ ws) {
    const int i = blockIdx.x * 256 + threadIdx.x;
    const float val = emaw[i] * DECAYF + ONEMF * ws[i];
    out[71369729 + i] = val;                               // new_ema_weight
    const float cs = out[71368705 + (i >> 6)];             // new_cs (from fin_cs)
    out[71303169 + i] = val / cs;                          // new_embedding
}

extern "C" void kernel_launch(void* const* d_in, const int* in_sizes, int n_in,
                              void* d_out, int out_size, void* d_ws, size_t ws_size,
                              hipStream_t stream) {
    const float* x    = (const float*)d_in[0];   // [16,64,64,64]
    const float* E    = (const float*)d_in[1];   // [1024,64]
    const float* cs   = (const float*)d_in[2];   // [1024]
    const float* emaw = (const float*)d_in[3];   // [1024,64]
    float* out = (float*)d_out;
    float* ws  = (float*)d_ws;

    prep_kernel<<<32, 256, 0, stream>>>(E, ws);
    vq_main<<<512, 256, 0, stream>>>(x, E, out, ws);
    fin_cs<<<1, 1024, 0, stream>>>(cs, out, ws);
    fin_w<<<256, 256, 0, stream>>>(emaw, out, ws);
}